// Round 2
// baseline (105.445 us; speedup 1.0000x reference)
//
#include <hip/hip_runtime.h>

#define NCLS 20
#define IGNORE_INDEX (-1)
#define TPB 128             // 2-wave blocks, fine-grain scheduling
#define PAIRS_PER_THREAD 8
#define PPB (TPB * PAIRS_PER_THREAD)   // 1024 pairs per block
#define CENTERS_PER_BLOCK (PPB / 16)   // 64 centers per block
#define RBITS 18            // n = 262144 = 2^18 -> neighbor index fits 18 bits
#define PSTRIDE 21          // 20 + 1 pad: 21 coprime 32 -> conflict-free column reads

typedef int iv4 __attribute__((ext_vector_type(4)));  // clang vector: OK for nontemporal

__device__ __forceinline__ void softmax_row(const float* __restrict__ row, float* v) {
    const float4* r4 = (const float4*)row;   // 80B rows, 16B-aligned
#pragma unroll
    for (int q = 0; q < 5; ++q) {
        float4 t = r4[q];
        v[4 * q + 0] = t.x; v[4 * q + 1] = t.y;
        v[4 * q + 2] = t.z; v[4 * q + 3] = t.w;
    }
    float mx = v[0];
#pragma unroll
    for (int c = 1; c < NCLS; ++c) mx = fmaxf(mx, v[c]);
    float s = 0.f;
#pragma unroll
    for (int c = 0; c < NCLS; ++c) { v[c] = __expf(v[c] - mx); s += v[c]; }
    float inv = 1.0f / s;
#pragma unroll
    for (int c = 0; c < NCLS; ++c) v[c] *= inv;
}

// R6 structure: scan+compact+process at 4096 x 128.
//  (a) center softmax computed ONCE per center into LDS (wave 0, 64 rows,
//      semi-coalesced loads) instead of per-survivor divergent gathers,
//  (b) ballot-compaction: <=8 LDS atomics per wave instead of ~25 serialized
//      divergent same-address atomics,
//  (c) non-temporal ref_idx loads (16.8 MB streamed once; keep L2 for
//      labels/logits which are re-gathered).
__global__ __launch_bounds__(TPB) void fused_kernel(
    const float* __restrict__ logits, const int* __restrict__ labels,
    const int* __restrict__ ref_idx,
    unsigned int* __restrict__ counts, float* __restrict__ partials,
    long long total_pairs) {
    __shared__ unsigned int s_buf[PPB];                        // 4 KB
    __shared__ float s_probs[CENTERS_PER_BLOCK][PSTRIDE];      // 5.25 KB
    __shared__ int s_cnt;
    __shared__ float s_wsum[TPB / 64];
    const int tid  = threadIdx.x;
    const int lane = tid & 63;
    if (tid == 0) s_cnt = 0;
    __syncthreads();

    // ---- phase 1a: scan 8 pairs (half of one point's neighborhood) ---------
    const long long pair0 = (long long)blockIdx.x * PPB + (long long)tid * 8;
    const bool inb = (pair0 + 8 <= total_pairs);
    int li = IGNORE_INDEX;
    int rr[8] = {-1, -1, -1, -1, -1, -1, -1, -1};
    int nl[8];
    if (inb) {
        const int p = (int)(pair0 >> 4);       // 8 | 16: all 8 pairs share one center
        li = labels[p];
        // streamed exactly once -> bypass L2 so labels/logits stay resident
        const iv4* rp = (const iv4*)(ref_idx + pair0);
        iv4 ra = __builtin_nontemporal_load(rp);
        iv4 rb = __builtin_nontemporal_load(rp + 1);
        rr[0] = ra.x; rr[1] = ra.y; rr[2] = ra.z; rr[3] = ra.w;
        rr[4] = rb.x; rr[5] = rb.y; rr[6] = rb.z; rr[7] = rb.w;
#pragma unroll
        for (int j = 0; j < 8; ++j) nl[j] = labels[max(rr[j], 0)];  // 8 independent gathers
    } else {
#pragma unroll
        for (int j = 0; j < 8; ++j) nl[j] = IGNORE_INDEX - 1;  // never matches li
    }

    // ---- phase 1b: this block's 64 center softmaxes -> LDS (wave 0 only) ---
    // 64 consecutive 80B rows (5 KB contiguous); overlaps the in-flight label
    // gathers above. Replaces ~51 divergent per-survivor center-row gathers +
    // softmaxes in phase 2.
    const int p0 = blockIdx.x * CENTERS_PER_BLOCK;
    if (tid < CENTERS_PER_BLOCK) {             // wave-uniform branch (tid<64)
        float v[NCLS];
        softmax_row(logits + (size_t)(p0 + tid) * NCLS, v);
#pragma unroll
        for (int c2 = 0; c2 < NCLS; ++c2) s_probs[tid][c2] = v[c2];
        // write pattern: lane t, step c -> addr 21*t+c; lanes t and t+32 alias
        // (2-way, free per m136); otherwise conflict-free (21 coprime 32)
    }

    // ---- survivor compaction: one ballot + <=1 LDS atomic per wave per j ---
    const unsigned long long lt_mask = (1ull << lane) - 1ull;
#pragma unroll
    for (int j = 0; j < 8; ++j) {
        const bool keep = (rr[j] >= 0) && (nl[j] == li) && (li != IGNORE_INDEX);
        unsigned long long m = __ballot(keep);   // straight-line: all 64 lanes vote
        int base = 0;
        if (lane == 0) {
            int tot = __popcll(m);
            if (tot) base = atomicAdd(&s_cnt, tot);
        }
        base = __shfl(base, 0, 64);
        if (keep) {
            int pre = __popcll(m & lt_mask);
            s_buf[base + pre] = ((unsigned int)(tid * 8 + j) << RBITS) |
                                (unsigned int)rr[j];
        }
    }
    __syncthreads();
    const int c = s_cnt;                        // <= PPB by construction

    // ---- phase 2: lane-dense pair processing; center probs from LDS --------
    float fsum = 0.f;
    for (int i = tid; i < c; i += TPB) {
        unsigned int e   = s_buf[i];
        unsigned int lid = e >> RBITS;                      // local pair id [0,1024)
        unsigned int r   = e & ((1u << RBITS) - 1u);        // neighbor index
        const float* pa  = s_probs[lid >> 4];               // center probs (LDS)
        float b[NCLS];
        softmax_row(logits + (size_t)r * NCLS, b);          // neighbor row gather
        float d = 0.f;
#pragma unroll
        for (int k = 0; k < NCLS; ++k) {
            float dx = pa[k] - b[k];
            d = fmaf(dx, dx, d);
        }
        fsum += d;
    }

    // ---- block reduction -> plain stores (no global atomics, R5) -----------
#pragma unroll
    for (int off = 32; off > 0; off >>= 1) fsum += __shfl_down(fsum, off, 64);
    if ((tid & 63) == 0) s_wsum[tid >> 6] = fsum;
    __syncthreads();
    if (tid == 0) {
        float t = 0.f;
#pragma unroll
        for (int w = 0; w < TPB / 64; ++w) t += s_wsum[w];
        partials[blockIdx.x] = t;
        counts[blockIdx.x] = (unsigned int)c;
    }
}

// ---- final single-block reduction ------------------------------------------
__global__ __launch_bounds__(1024) void reduce_kernel(
    const float* __restrict__ partials, const unsigned int* __restrict__ counts,
    float* __restrict__ out, int m) {
    double dsum = 0.0;
    unsigned long long cnt = 0;
    for (int i = threadIdx.x; i < m; i += 1024) {
        dsum += (double)partials[i];
        // clamp: counts may be 0xAA-poisoned in an isolated rocprof replay
        cnt  += (unsigned long long)min(counts[i], (unsigned int)PPB);
    }
#pragma unroll
    for (int off = 32; off > 0; off >>= 1) {
        dsum += __shfl_down(dsum, off, 64);
        cnt  += __shfl_down(cnt,  off, 64);
    }
    __shared__ double s_sum[16];
    __shared__ unsigned long long s_cnt[16];
    const int wave = threadIdx.x >> 6;
    if ((threadIdx.x & 63) == 0) { s_sum[wave] = dsum; s_cnt[wave] = cnt; }
    __syncthreads();
    if (threadIdx.x == 0) {
        double ts = 0.0; unsigned long long tc = 0;
        for (int w = 0; w < 16; ++w) { ts += s_sum[w]; tc += s_cnt[w]; }
        if (tc < 1ull) tc = 1ull;
        out[0] = (float)(ts / (double)tc);     // LOSS_WEIGHT = 1.0
    }
}

extern "C" void kernel_launch(void* const* d_in, const int* in_sizes, int n_in,
                              void* d_out, int out_size, void* d_ws, size_t ws_size,
                              hipStream_t stream) {
    const float* seg_logits = (const float*)d_in[0];
    // d_in[1] = coord — unused (KNN indices are given)
    const int* labels  = (const int*)d_in[2];
    const int* ref_idx = (const int*)d_in[3];
    float* out = (float*)d_out;
    const int n = in_sizes[2];                       // 262144
    const long long total_pairs = (long long)n * 16; // 4,194,304
    const int blocks = (int)((total_pairs + PPB - 1) / PPB);   // 4096

    // ws layout: counts[blocks] | partials[blocks]  (32 KB of the 256 MiB ws)
    unsigned int* counts = (unsigned int*)d_ws;
    float* partials      = (float*)((char*)d_ws + (size_t)blocks * 4);

    fused_kernel<<<blocks, TPB, 0, stream>>>(seg_logits, labels, ref_idx,
                                             counts, partials, total_pairs);
    reduce_kernel<<<1, 1024, 0, stream>>>(partials, counts, out, blocks);
}